// Round 13
// baseline (11587.851 us; speedup 1.0000x reference)
//
#include <hip/hip_runtime.h>

// Pointer network: encoder LSTM -> enc_proj -> decoder LSTM + attention argmax.
// B=512, S=100, D=2, H=256.
//
// NUMERICS (FROZEN since R7, absmax 7.0 <= 7.2): f64 state trajectory (h/c/
// gates/ep/dp in f64; chain ORDER may vary -- error ~1e-13 << decision gaps)
// + EXACT np-faithful fp32 log_softmax selection (single f32 rounding of
// scores, pairwise-8 sum of exps, lp=fl(fl(s-m)-L), argmax(lp) first-index,
// lp_acc sequential fp32). Selection block below is byte-identical to R7-R12.
//
// R13: ep REGISTER-RESIDENT. R12's FETCH was 2.84GB, ~2.6GB of it decoder ep
// re-reads (50 rows x 2KB x 100 steps x 512 blocks; per-XCD slab footprint
// 12.8MB >> 4MB L2 -> always misses). Same stream from HBM on cold-L3 replays
// = the 43ms outlier dispatches (harness re-poisons ws each launch). Fix:
// thread u needs exactly ep[b][s][u], s=0..99 -> double epreg[100] = 200
// VGPRs. launch_bounds(256,2) caps at 256 VGPR; occupancy stays 2 blocks/CU
// (grid=512 is dispatch-limited there anyway). ep written once (105MB,
// block-private), read back ONCE into registers via fully-unrolled loop;
// score loop fully unrolled so all epreg indices are compile-time (dynamic
// index would spill the array -- the failure mode to watch in VGPR_Count).
// Values bit-identical to R12.
//
// 512 blocks x 256 threads, plain launches, no co-residency requirement.

#define B_WHE  0ull                       // f32 [256 k][256 u][4 g] enc Whh^T
#define B_WHD  (B_WHE + 1048576ull)       // f32 dec
#define B_WET  (B_WHD + 1048576ull)       // f32 [256 k][256 u] We^T
#define B_WDT  (B_WET + 262144ull)        // f32 Wd^T
#define B_WXE  (B_WDT + 262144ull)        // f64 [256 u][16] Wih+bias pack
#define B_WXD  (B_WXE + 32768ull)
#define B_EP   (B_WXD + 32768ull)         // f64 [512 b][100 t][256 u] = 104.9MB

__device__ __forceinline__ double sigmoid_d(double x) {
  return 1.0 / (1.0 + exp(-x));
}

__device__ __forceinline__ double shfl_xor_d(double v, int m) {
  const long long l = __double_as_longlong(v);
  int lo = (int)(l & 0xffffffffll), hi = (int)(l >> 32);
  lo = __shfl_xor(lo, m, 64);
  hi = __shfl_xor(hi, m, 64);
  return __longlong_as_double(((long long)hi << 32) | (unsigned int)lo);
}

__device__ __forceinline__ double wave64_sum_d(double v) {
  #pragma unroll
  for (int m = 1; m < 64; m <<= 1) v += shfl_xor_d(v, m);
  return v;
}

struct SMem {
  double sred[100][4];
  float  scores[104];
  float  evals[104];
  float  red_m, red_L;
  float  bc_lp;
  int    bc_sel;
};

extern "C" __global__ void ptrnet_prep(
    const float* __restrict__ eWih, const float* __restrict__ eWhh,
    const float* __restrict__ ebih, const float* __restrict__ ebhh,
    const float* __restrict__ dWih, const float* __restrict__ dWhh,
    const float* __restrict__ dbih, const float* __restrict__ dbhh,
    const float* __restrict__ We,  const float* __restrict__ Wd,
    char* __restrict__ wsb)
{
  const int idx = blockIdx.x * blockDim.x + threadIdx.x;
  const int stride = gridDim.x * blockDim.x;
  float* WHE = (float*)(wsb + B_WHE);
  float* WHD = (float*)(wsb + B_WHD);
  float* WET = (float*)(wsb + B_WET);
  float* WDT = (float*)(wsb + B_WDT);
  double* WXE = (double*)(wsb + B_WXE);
  double* WXD = (double*)(wsb + B_WXD);

  // Whh^T packs: [k][u][gate] (f32 verbatim -- exact)
  for (int i = idx; i < 256*256*4; i += stride) {
    const int g = i & 3, u = (i >> 2) & 255, k = i >> 10;
    WHE[i] = eWhh[(g*256 + u)*256 + k];
    WHD[i] = dWhh[(g*256 + u)*256 + k];
  }
  // We^T / Wd^T: [k][u]
  for (int i = idx; i < 256*256; i += stride) {
    const int u = i & 255, k = i >> 8;
    WET[i] = We[u*256 + k];
    WDT[i] = Wd[u*256 + k];
  }
  // Wih + bias pack (f64): [u][16] = {i0,i1,f0,f1,g0,g1,o0,o1, bi,bf,bg,bo}
  for (int i = idx; i < 256*16; i += stride) {
    const int f = i & 15, u = i >> 4;
    double ve = 0.0, vd = 0.0;
    if (f < 8) {
      const int gg = f >> 1, d = f & 1;
      ve = (double)eWih[(gg*256+u)*2 + d];
      vd = (double)dWih[(gg*256+u)*2 + d];
    } else if (f < 12) {
      const int gg = f - 8;
      ve = (double)ebih[gg*256+u] + (double)ebhh[gg*256+u];
      vd = (double)dbih[gg*256+u] + (double)dbhh[gg*256+u];
    }
    WXE[i] = ve;
    WXD[i] = vd;
  }
}

extern "C" __global__ void __launch_bounds__(256, 2)
ptrnet_main(char* __restrict__ wsb,
            const float* __restrict__ x,
            const float* __restrict__ be,
            const float* __restrict__ bd,
            const float* __restrict__ Vw,
            const float* __restrict__ Vb,
            const float* __restrict__ start,
            float* __restrict__ out)
{
  __shared__ double hls[2][256];   // block-private h state, ping-pong
  __shared__ SMem sm;
  __shared__ float s_din[2];
  const int b   = blockIdx.x;      // one block per batch element
  const int tid = threadIdx.x;     // thread = hidden unit u
  const int lane = tid & 63;
  const int w = __builtin_amdgcn_readfirstlane(tid >> 6);

  const float* WHE = (const float*)(wsb + B_WHE);
  const float* WHD = (const float*)(wsb + B_WHD);
  const float* WET = (const float*)(wsb + B_WET);
  const float* WDT = (const float*)(wsb + B_WDT);
  const double* wxE = (const double*)(wsb + B_WXE) + tid*16;
  const double* wxD = (const double*)(wsb + B_WXD) + tid*16;
  double* ep = (double*)(wsb + B_EP) + (size_t)b*25600;   // block-private

  const double be_u = (double)be[tid];
  const double bd_u = (double)bd[tid];
  const double vw_r = (double)Vw[tid];
  const double vb0  = (double)Vb[0];

  double c_state = 0.0;
  int par = 0;
  hls[0][tid] = 0.0;
  if (tid < 2) s_din[tid] = start[tid];
  __syncthreads();

  // ============================ encoder ============================
  for (int t = 0; t < 100; ++t) {
    const double x0 = (double)x[(b*100 + t)*2 + 0];
    const double x1 = (double)x[(b*100 + t)*2 + 1];
    double a0 = 0.0, a1 = 0.0, a2 = 0.0, a3 = 0.0, ae = 0.0;
    const double* hrow = hls[par];
    #pragma unroll 4
    for (int k = 0; k < 256; ++k) {
      const double hk = hrow[k];                       // LDS broadcast
      const float4 wf = *(const float4*)(WHE + k*1024 + tid*4);
      const float  we = WET[k*256 + tid];
      a0 = fma((double)wf.x, hk, a0);
      a1 = fma((double)wf.y, hk, a1);
      a2 = fma((double)wf.z, hk, a2);
      a3 = fma((double)wf.w, hk, a3);
      ae = fma((double)we,  hk, ae);
    }
    const double gi = a0 + fma(wxE[0], x0, fma(wxE[1], x1, wxE[8]));
    const double gf = a1 + fma(wxE[2], x0, fma(wxE[3], x1, wxE[9]));
    const double gg = a2 + fma(wxE[4], x0, fma(wxE[5], x1, wxE[10]));
    const double go = a3 + fma(wxE[6], x0, fma(wxE[7], x1, wxE[11]));
    const double cn = sigmoid_d(gf)*c_state + sigmoid_d(gi)*tanh(gg);
    const double hn = sigmoid_d(go)*tanh(cn);
    c_state = cn;
    if (t > 0) ep[(t-1)*256 + tid] = ae + be_u;   // ep[t-1] = We*h^(t)+be
    hls[par ^ 1][tid] = hn;
    __syncthreads();
    par ^= 1;
  }
  // ep[99] from h^(100)
  {
    double ae = 0.0;
    const double* hrow = hls[par];
    #pragma unroll 4
    for (int k = 0; k < 256; ++k)
      ae = fma((double)WET[k*256 + tid], hrow[k], ae);
    ep[99*256 + tid] = ae + be_u;
  }

  // ---- ep -> registers, ONCE (105MB total vs 2.6GB of per-step re-reads).
  // All indices compile-time (full unroll) so the array maps to 200 VGPRs.
  double epreg[100];
  #pragma unroll
  for (int s = 0; s < 100; ++s) epreg[s] = ep[s*256 + tid];

  // ===================== decoder =====================
  unsigned long long m0 = 0ull, m1 = 0ull;
  float lp_acc = 0.0f;

  for (int t = 0; t < 100; ++t) {
    // ---------- LSTM cell ----------
    {
      const double x0 = (double)s_din[0];
      const double x1 = (double)s_din[1];
      double a0 = 0.0, a1 = 0.0, a2 = 0.0, a3 = 0.0;
      const double* hrow = hls[par];
      #pragma unroll 4
      for (int k = 0; k < 256; ++k) {
        const double hk = hrow[k];
        const float4 wf = *(const float4*)(WHD + k*1024 + tid*4);
        a0 = fma((double)wf.x, hk, a0);
        a1 = fma((double)wf.y, hk, a1);
        a2 = fma((double)wf.z, hk, a2);
        a3 = fma((double)wf.w, hk, a3);
      }
      const double gi = a0 + fma(wxD[0], x0, fma(wxD[1], x1, wxD[8]));
      const double gf = a1 + fma(wxD[2], x0, fma(wxD[3], x1, wxD[9]));
      const double gg = a2 + fma(wxD[4], x0, fma(wxD[5], x1, wxD[10]));
      const double go = a3 + fma(wxD[6], x0, fma(wxD[7], x1, wxD[11]));
      const double cn = sigmoid_d(gf)*c_state + sigmoid_d(gi)*tanh(gg);
      const double hn = sigmoid_d(go)*tanh(cn);
      c_state = cn;
      hls[par ^ 1][tid] = hn;
      __syncthreads();
      par ^= 1;
    }
    // ---------- dec_proj row (block-local) ----------
    double dpl;
    {
      double ad = 0.0;
      const double* hrow = hls[par];
      #pragma unroll 4
      for (int k = 0; k < 256; ++k)
        ad = fma((double)WDT[k*256 + tid], hrow[k], ad);
      dpl = ad + bd_u;
    }
    // ---------- f64-exact scores -> np-faithful fp32 log_softmax ----------
    {
      #pragma unroll
      for (int s = 0; s < 100; ++s) {
        const bool masked = (s < 64) ? (((m0 >> s) & 1ull) != 0ull)
                                     : (((m1 >> (s-64)) & 1ull) != 0ull);
        if (!masked) {   // block-uniform -> whole-wave skip
          double p = tanh(epreg[s] + dpl) * vw_r;   // register-resident ep
          p = wave64_sum_d(p);
          if (lane == 0) sm.sred[s][w] = p;
        }
      }
      __syncthreads();
      if (tid < 100) {
        const bool masked = (tid < 64) ? (((m0 >> tid) & 1ull) != 0ull)
                                       : (((m1 >> (tid-64)) & 1ull) != 0ull);
        // single rounding of the exact score to fp32 (reference dtype)
        sm.scores[tid] = masked ? -__builtin_inff()
                                : (float)(sm.sred[tid][0] + sm.sred[tid][1] +
                                          sm.sred[tid][2] + sm.sred[tid][3] + vb0);
      }
      __syncthreads();
      if (w == 0) {   // m = max(scores), fp32
        const float v0 = sm.scores[lane];
        const float v1 = (lane < 36) ? sm.scores[64 + lane] : -__builtin_inff();
        float mv = fmaxf(v0, v1);
        #pragma unroll
        for (int mm = 1; mm < 64; mm <<= 1)
          mv = fmaxf(mv, __shfl_xor(mv, mm, 64));
        if (lane == 0) sm.red_m = mv;
      }
      __syncthreads();
      if (tid < 100)
        sm.evals[tid] = expf(__fsub_rn(sm.scores[tid], sm.red_m));
      __syncthreads();
      if (tid == 0) {
        // numpy pairwise_sum for n=100: 8 accumulators over 0..95,
        // combine ((r0+r1)+(r2+r3))+((r4+r5)+(r6+r7)), sequential tail 96..99
        float rr[8];
        #pragma unroll
        for (int j = 0; j < 8; ++j) rr[j] = sm.evals[j];
        for (int i = 8; i < 96; i += 8) {
          #pragma unroll
          for (int j = 0; j < 8; ++j) rr[j] = __fadd_rn(rr[j], sm.evals[i + j]);
        }
        float res = __fadd_rn(
            __fadd_rn(__fadd_rn(rr[0], rr[1]), __fadd_rn(rr[2], rr[3])),
            __fadd_rn(__fadd_rn(rr[4], rr[5]), __fadd_rn(rr[6], rr[7])));
        res = __fadd_rn(res, sm.evals[96]);
        res = __fadd_rn(res, sm.evals[97]);
        res = __fadd_rn(res, sm.evals[98]);
        res = __fadd_rn(res, sm.evals[99]);
        sm.red_L = logf(res);
      }
      __syncthreads();
      if (w == 0) {   // lp = fl(fl(s - m) - L); argmax(lp), first index on ties
        const float m = sm.red_m, L = sm.red_L;
        const float lp0 = __fsub_rn(__fsub_rn(sm.scores[lane], m), L);
        const float lp1 = (lane < 36)
            ? __fsub_rn(__fsub_rn(sm.scores[64 + lane], m), L)
            : -__builtin_inff();
        float bv; int bi;
        if (lp0 >= lp1) { bv = lp0; bi = lane; } else { bv = lp1; bi = 64 + lane; }
        #pragma unroll
        for (int mm = 1; mm < 64; mm <<= 1) {
          const float ov = __shfl_xor(bv, mm, 64);
          const int   oi = __shfl_xor(bi, mm, 64);
          if (ov > bv || (ov == bv && oi < bi)) { bv = ov; bi = oi; }
        }
        if (lane == 0) { sm.bc_sel = bi; sm.bc_lp = bv; }
      }
      __syncthreads();
      const int sel = __builtin_amdgcn_readfirstlane(sm.bc_sel);
      lp_acc = __fadd_rn(lp_acc, sm.bc_lp);   // np axis-0 sum: sequential fp32
      if (sel < 64) m0 |= (1ull << sel); else m1 |= (1ull << (sel - 64));
      if (tid == 0) out[b*100 + t] = (float)sel;
      if (tid < 2) s_din[tid] = x[(b*100 + sel)*2 + tid];
      __syncthreads();
    }
  }

  // ---------------- outputs ----------------
  if (tid == 0) out[51200 + b] = lp_acc;
  out[51712 + b*256 + tid] = (float)hls[par][tid];
}

extern "C" void kernel_launch(void* const* d_in, const int* in_sizes, int n_in,
                              void* d_out, int out_size, void* d_ws, size_t ws_size,
                              hipStream_t stream) {
  const float* x     = (const float*)d_in[0];
  const float* eWih  = (const float*)d_in[1];
  const float* eWhh  = (const float*)d_in[2];
  const float* ebih  = (const float*)d_in[3];
  const float* ebhh  = (const float*)d_in[4];
  const float* dWih  = (const float*)d_in[5];
  const float* dWhh  = (const float*)d_in[6];
  const float* dbih  = (const float*)d_in[7];
  const float* dbhh  = (const float*)d_in[8];
  const float* We    = (const float*)d_in[9];
  const float* be    = (const float*)d_in[10];
  const float* Wd    = (const float*)d_in[11];
  const float* bd    = (const float*)d_in[12];
  const float* vw    = (const float*)d_in[13];
  const float* vb    = (const float*)d_in[14];
  const float* start = (const float*)d_in[15];
  char* ws    = (char*)d_ws;
  float* outp = (float*)d_out;

  ptrnet_prep<<<dim3(512), dim3(256), 0, stream>>>(
      eWih, eWhh, ebih, ebhh, dWih, dWhh, dbih, dbhh, We, Wd, ws);

  ptrnet_main<<<dim3(512), dim3(256), 0, stream>>>(ws, x, be, bd, vw, vb,
                                                   start, outp);
}